// Round 15
// baseline (4345.784 us; speedup 1.0000x reference)
//
#include <hip/hip_runtime.h>
#include <hip/hip_bf16.h>
#include <math.h>

// ---------------------------------------------------------------------------
// Bi-LSTM encoder (final states only) -> 2-layer AR decoder (64 steps) -> vocab-3.
//   init_k         : sentinel encoder pair-rings + decoder rings r0/r1
//   convert_k      : x, ew_ih_{f,b} -> f16; bias sums
//   convert_we4_k  : enc W_hh -> fan-2 gate-interleaved MFMA A-frags (f16)
//   convert_wdec_k : dec [W_ih|W_hh] both layers -> gate-interleaved A-frags (f16)
//   xproj_gemm     : f16 MFMA GEMM -> Xproj[dir][t][b][1024] fp32 (+bias), dir1 reversed
//   encoder_k      : v11 — FAN-2 ring: 32 blocks (d x bg x half), 512 thr, each owns
//                    128 h-cols (32 frags = 128 VGPR); pair exchanges 4KB/step via
//                    depth-4 sentinel ring (1 u64 store + 1 u64 poll per thread);
//                    own half stays in LDS. R12 prefetch placement (post-store).
//   decoder_k      : v3b (R12-proven) — dual-layer blocks, two sentinel rings
//   logits_k       : h1 history @ lw^T + lb
// ---------------------------------------------------------------------------

typedef unsigned short u16;
typedef unsigned int u32;
typedef unsigned long long u64;
typedef _Float16 f16;
typedef f16 f16x8 __attribute__((ext_vector_type(8)));
typedef u16 u16x8 __attribute__((ext_vector_type(8)));
typedef u32 u32x4 __attribute__((ext_vector_type(4)));
typedef float f32x4 __attribute__((ext_vector_type(4)));

__device__ __forceinline__ u16 f2h(float f) {
  return __builtin_bit_cast(unsigned short, (f16)f);
}
__device__ __forceinline__ float h2f(u16 h) {
  return (float)__builtin_bit_cast(f16, h);
}
__device__ __forceinline__ u32 packf16(float a, float b) {
  return (u32)f2h(a) | ((u32)f2h(b) << 16);
}
__device__ __forceinline__ u64 ald64(const u64* p) {
  return __hip_atomic_load(p, __ATOMIC_RELAXED, __HIP_MEMORY_SCOPE_AGENT);
}
__device__ __forceinline__ void ast64(u64* p, u64 v) {
  __hip_atomic_store(p, v, __ATOMIC_RELAXED, __HIP_MEMORY_SCOPE_AGENT);
}

#define SENT 0xFFFFFFFFFFFFFFFFull   // f16 NaN quad: unreachable for h in (-1,1)

// ---------------------------------------------------------------------------
__global__ __launch_bounds__(256) void init_k(u32* hglob, u32* r0, u32* r1) {
  int gid = blockIdx.x * 256 + threadIdx.x;   // grid 1024*256 = 262144
  if (gid < 131072)       hglob[gid] = 0xFFFFFFFFu;   // enc rings [32][4][512 u64]
  else if (gid < 196608)  r0[gid - 131072] = 0xFFFFFFFFu;
  else                    r1[gid - 196608] = 0xFFFFFFFFu;
}

// ---------------------------------------------------------------------------
__global__ __launch_bounds__(256) void convert_k(
    const float* __restrict__ x,
    const float* __restrict__ wfm, const float* __restrict__ wbm,
    const float* __restrict__ bif, const float* __restrict__ bhf,
    const float* __restrict__ bib, const float* __restrict__ bhb,
    const float* __restrict__ dbi0, const float* __restrict__ dbh0,
    const float* __restrict__ dbi1, const float* __restrict__ dbh1,
    u16* __restrict__ xh, u16* __restrict__ wh,
    float* __restrict__ bias2, float* __restrict__ dbias) {
  const long NX = 67108864L, NW = 1048576L;
  long gid = (long)blockIdx.x * 256 + threadIdx.x;
  if (gid < 1024) {
    bias2[gid]        = bif[gid] + bhf[gid];
    bias2[1024 + gid] = bib[gid] + bhb[gid];
    dbias[gid]        = dbi0[gid] + dbh0[gid];
    dbias[1024 + gid] = dbi1[gid] + dbh1[gid];
  }
  long total4 = (NX + 2 * NW) >> 2;
  long stride = (long)gridDim.x * 256;
  for (long q = gid; q < total4; q += stride) {
    long i = q << 2;
    const float* src; u16* dst; long o;
    if (i < NX)            { src = x;   dst = xh;      o = i; }
    else if (i < NX + NW)  { src = wfm; dst = wh;      o = i - NX; }
    else                   { src = wbm; dst = wh + NW; o = i - NX - NW; }
    float4 v = *(const float4*)&src[o];
    dst[o + 0] = f2h(v.x); dst[o + 1] = f2h(v.y);
    dst[o + 2] = f2h(v.z); dst[o + 3] = f2h(v.w);
  }
}

// ---------------------------------------------------------------------------
// enc W_hh -> fan-2 gate-interleaved A-fragments:
//   wenc4[d][half][w8][tile4][ks8][lane][j] = W_hh_d[gcol][k]
//   ri = lane&15; gcol = (ri&3)*256 + half*128 + w*16 + tile*4 + (ri>>2);
//   k = ks*32 + (lane>>4)*8 + j.
__global__ __launch_bounds__(256) void convert_we4_k(
    const float* __restrict__ whf, const float* __restrict__ whb,
    u16* __restrict__ wenc4) {
  int o = blockIdx.x * 256 + threadIdx.x;     // grid 2048*256 = 524288
  int j = o & 7, lane = (o >> 3) & 63, ks = (o >> 9) & 7;
  int tile = (o >> 12) & 3, w = (o >> 14) & 7, half = (o >> 17) & 1, d = o >> 18;
  int ri = lane & 15;
  int gcol = (ri & 3) * 256 + half * 128 + w * 16 + tile * 4 + (ri >> 2);
  int k = ks * 32 + (lane >> 4) * 8 + j;
  const float* wsrc = d ? whb : whf;
  wenc4[o] = f2h(wsrc[gcol * 256 + k]);
}

// ---------------------------------------------------------------------------
// dec [W_ih|W_hh] (K=512) both layers -> gate-interleaved A-fragments.
__global__ __launch_bounds__(256) void convert_wdec_k(
    const float* __restrict__ wi0, const float* __restrict__ wh0,
    const float* __restrict__ wi1, const float* __restrict__ wh1,
    u16* __restrict__ wdec) {
  int o = blockIdx.x * 256 + threadIdx.x;     // grid 4096*256 = 1048576
  int j = o & 7, lane = (o >> 3) & 63, ks = (o >> 9) & 15;
  int w = (o >> 13) & 3, cg = (o >> 15) & 15, L = o >> 19;
  int ri = lane & 15;
  int row = (ri & 3) * 256 + cg * 16 + w * 4 + (ri >> 2);
  int k = ks * 32 + (lane >> 4) * 8 + j;
  const float* wi = L ? wi1 : wi0;
  const float* wh = L ? wh1 : wh0;
  float v = (k < 256) ? wi[row * 256 + k] : wh[row * 256 + k - 256];
  wdec[o] = f2h(v);
}

// ---------------------------------------------------------------------------
// Xproj GEMM (f16): C = X @ W^T + bias, 128x128 tiles, mfma_f32_16x16x32_f16.
__global__ __launch_bounds__(256) void xproj_gemm(
    const u16* __restrict__ xh, const u16* __restrict__ wh,
    const float* __restrict__ bias2, float* __restrict__ xp) {
  __shared__ u16 Al[128][40];
  __shared__ u16 Bl[128][40];
  int bid = blockIdx.x;
  int dir = bid >> 12, rem = bid & 4095, tb = rem >> 3, nb = rem & 7;
  int tsrc = dir ? (511 - tb) : tb;
  const u16* A  = xh + (long)tsrc * (128 * 1024);
  const u16* Bw = wh + (long)dir * (1024 * 1024) + (long)nb * (128 * 1024);
  float* C = xp + ((long)(dir * 512 + tb) * 128) * 1024 + nb * 128;
  const float* bias = bias2 + dir * 1024 + nb * 128;

  int tid = threadIdx.x, lane = tid & 63, wid = tid >> 6;
  int wr = wid >> 1, wc = wid & 1;
  int srow = tid >> 1, scol = (tid & 1) * 16;
  int fr = lane & 15, ko = lane >> 4;

  f32x4 acc[4][4] = {};
  for (int k0 = 0; k0 < 1024; k0 += 32) {
    u16x8 a0 = *(const u16x8*)&A[(long)srow * 1024 + k0 + scol];
    u16x8 a1 = *(const u16x8*)&A[(long)srow * 1024 + k0 + scol + 8];
    u16x8 b0 = *(const u16x8*)&Bw[(long)srow * 1024 + k0 + scol];
    u16x8 b1 = *(const u16x8*)&Bw[(long)srow * 1024 + k0 + scol + 8];
    __syncthreads();
    *(u16x8*)&Al[srow][scol]     = a0;
    *(u16x8*)&Al[srow][scol + 8] = a1;
    *(u16x8*)&Bl[srow][scol]     = b0;
    *(u16x8*)&Bl[srow][scol + 8] = b1;
    __syncthreads();
    f16x8 af[4], bf[4];
#pragma unroll
    for (int i = 0; i < 4; ++i)
      af[i] = __builtin_bit_cast(f16x8, *(const u16x8*)&Al[wr * 64 + i * 16 + fr][ko * 8]);
#pragma unroll
    for (int jf = 0; jf < 4; ++jf)
      bf[jf] = __builtin_bit_cast(f16x8, *(const u16x8*)&Bl[wc * 64 + jf * 16 + fr][ko * 8]);
#pragma unroll
    for (int i = 0; i < 4; ++i)
#pragma unroll
      for (int jf = 0; jf < 4; ++jf)
        acc[i][jf] = __builtin_amdgcn_mfma_f32_16x16x32_f16(af[i], bf[jf], acc[i][jf], 0, 0, 0);
  }
  int fq = lane >> 4;
#pragma unroll
  for (int i = 0; i < 4; ++i)
#pragma unroll
    for (int jf = 0; jf < 4; ++jf) {
      int col = wc * 64 + jf * 16 + fr;
      float bv = bias[col];
#pragma unroll
      for (int e = 0; e < 4; ++e) {
        int row = wr * 64 + i * 16 + fq * 4 + e;
        C[(long)row * 1024 + col] = acc[i][jf][e] + bv;
      }
    }
}

// ---------------------------------------------------------------------------
// Encoder v11 (fan-2): 32 blocks = d(2) x bg(8; 16 rows) x half(2; 128 hcols),
// 512 threads (8 waves). Wave w owns 16 cols = 4 tiles; 32 frags = 128 VGPR.
// Per step: poll partner 4KB (1 u64/thread) -> re-arm own (t+2) -> partner half
// -> LDS image; barrier; 32 MFMA/wave + 4 in-register cells; stage; barrier;
// vmcnt(0); store own 4KB burst (slot t+1) + own half -> LDS image; xp prefetch.
// Depth-4 sentinel ring protocol identical to v9b (fan=2).
__global__ __launch_bounds__(512, 2) void encoder_k(
    const u16* __restrict__ wenc4, const float* __restrict__ xp,
    u32* hglob,
    float* h0b, float* h1b, float* cfb, float* cbb) {
  int b = blockIdx.x;                       // 0..31
  int d = b >> 4, bg = (b >> 1) & 7, half = b & 1;
  int tid = threadIdx.x, lane = tid & 63, w = tid >> 6;
  int brow = lane & 15, lq = lane >> 4;
  int hswz = (brow & 7) << 4;
  int ohb = half * 256;                     // own-half byte base in image row
  int phb = (half ^ 1) * 256;               // partner-half byte base

  __shared__ __align__(16) char hlds[2][8192];   // h [16 r][256 c] f16, swizzled, dbuf
  __shared__ __align__(16) u16 hstage[16][128];  // own-half h_{t+1} stage (4KB)

  f16x8 wfr[32];                                 // 128 VGPR, statically indexed
#pragma unroll
  for (int tile = 0; tile < 4; ++tile) {
    const u16* wb = wenc4 + ((((long)(d * 2 + half) * 8 + w) * 4 + tile)) * 4096 + lane * 8;
#pragma unroll
    for (int ks = 0; ks < 8; ++ks)
      wfr[tile * 8 + ks] = __builtin_bit_cast(f16x8, *(const u16x8*)(wb + (long)ks * 512));
  }

  float c_state[4];
#pragma unroll
  for (int i = 0; i < 4; ++i) c_state[i] = 0.f;

  // xp addressing: row = bg*16+brow; gcol(tile,g) = g*256 + half*128 + w*16 + tile*4 + lq
  long xprow = ((long)(d * 512) * 128 + bg * 16 + brow) * 1024;
  int xcol0 = half * 128 + w * 16 + lq;
  float xpv[4][4];
#pragma unroll
  for (int tile = 0; tile < 4; ++tile)
#pragma unroll
    for (int g = 0; g < 4; ++g)
      xpv[tile][g] = xp[xprow + g * 256 + xcol0 + tile * 4];

  u64* hg = (u64*)hglob;                    // [32 ring][4 slot][512 u64]
  long orbase = (long)(((d * 8 + bg) * 2) + half) * 2048;
  long prbase = (long)(((d * 8 + bg) * 2) + (half ^ 1)) * 2048;
  int srow2 = tid >> 5, scolq = tid & 31;   // store/gather decode: 8B each
  __syncthreads();

  for (int t = 0; t < 512; ++t) {
    if (t != 0) {
      // --- poll partner half of h_t: single u64 per thread ---
      const u64* pp = hg + prbase + (long)(t & 3) * 512 + tid;
      u64 v = ald64(pp);
      while (v == SENT) v = ald64(pp);
      // re-arm my word in my slot (t+2)&3 (holds my consumed h_{t-2})
      ast64(hg + orbase + (long)((t + 2) & 3) * 512 + tid, SENT);
      // partner half -> image (8B swizzled write; stays within 16B granule)
      *(u64*)(hlds[t & 1] + ((srow2 * 512 + phb + scolq * 8) ^ ((srow2 & 7) << 4))) = v;
    }
    __syncthreads();

    // --- 32 MFMAs/wave (4 independent tile chains) ---
    f32x4 acc[4] = {};
    if (t != 0) {
      const char* hrd = hlds[t & 1];
#pragma unroll
      for (int ks = 0; ks < 8; ++ks) {
        f16x8 hf = *(const f16x8*)(hrd + ((brow * 512 + ks * 64 + lq * 16) ^ hswz));
#pragma unroll
        for (int tile = 0; tile < 4; ++tile)
          acc[tile] = __builtin_amdgcn_mfma_f32_16x16x32_f16(wfr[tile * 8 + ks], hf, acc[tile], 0, 0, 0);
      }
    }

    // --- 4 in-register LSTM cells: cell (brow, half*128 + w*16 + tile*4 + lq) ---
#pragma unroll
    for (int tile = 0; tile < 4; ++tile) {
      float iv = 1.f / (1.f + expf(-(acc[tile][0] + xpv[tile][0])));
      float fv = 1.f / (1.f + expf(-(acc[tile][1] + xpv[tile][1])));
      float gg = tanhf(acc[tile][2] + xpv[tile][2]);
      float ov = 1.f / (1.f + expf(-(acc[tile][3] + xpv[tile][3])));
      float c2 = fv * c_state[tile] + iv * gg;
      c_state[tile] = c2;
      float hval = ov * tanhf(c2);
      if (t < 511) {
        hstage[brow][w * 16 + tile * 4 + lq] = f2h(hval);
      } else {
        int rowg = bg * 16 + brow, colg = half * 128 + w * 16 + tile * 4 + lq;
        (d ? h1b : h0b)[32768 + rowg * 256 + colg] = hval;  // decoder init slot
        (d ? cbb : cfb)[rowg * 256 + colg] = c_state[tile];
      }
    }

    if (t < 511) {
      __syncthreads();
      // release: re-arm (and prior VMEM) complete before data store
      asm volatile("s_waitcnt vmcnt(0)" ::: "memory");
      u64 sv = *(const u64*)&hstage[srow2][scolq * 4];
      ast64(hg + orbase + (long)((t + 1) & 3) * 512 + tid, sv);   // 4KB burst
      // own half -> next image directly (no round trip)
      *(u64*)(hlds[(t + 1) & 1] + ((srow2 * 512 + ohb + scolq * 8) ^ ((srow2 & 7) << 4))) = sv;
      // prefetch xp[t+1] (R12-proven placement: after the store)
      long xb2 = xprow + (long)(t + 1) * 131072;
#pragma unroll
      for (int tile = 0; tile < 4; ++tile)
#pragma unroll
        for (int g = 0; g < 4; ++g)
          xpv[tile][g] = xp[xb2 + g * 256 + xcol0 + tile * 4];
    }
  }
}

// ---------------------------------------------------------------------------
// Decoder v3b (R12-proven, unchanged).
__global__ __launch_bounds__(256, 1) void decoder_k(
    const u16* __restrict__ wdec, const float* __restrict__ dbias,
    const float* __restrict__ h0b, const float* __restrict__ h1b,
    const float* __restrict__ cfb, const float* __restrict__ cbb,
    u32* r0, u32* r1, float* __restrict__ hist) {
  int b = blockIdx.x;
  int bg = b & 7, cg = b >> 3;
  int tid = threadIdx.x, lane = tid & 63, w = tid >> 6;
  int brow = lane & 15, lq = lane >> 4;
  int hswz = (brow & 7) << 4;
  int col = cg * 16 + w * 4 + lq;

  __shared__ __align__(16) char hA[8192];
  __shared__ __align__(16) char hB[8192];
  __shared__ __align__(16) u16 hstage[16][16];

  f16x8 w0[16], w1[16];
  {
    const u16* p0 = wdec + ((long)(cg * 4 + w)) * 8192 + lane * 8;
    const u16* p1 = wdec + ((long)((16 + cg) * 4 + w)) * 8192 + lane * 8;
#pragma unroll
    for (int ks = 0; ks < 16; ++ks) {
      w0[ks] = __builtin_bit_cast(f16x8, *(const u16x8*)(p0 + (long)ks * 512));
      w1[ks] = __builtin_bit_cast(f16x8, *(const u16x8*)(p1 + (long)ks * 512));
    }
  }
  float b0[4], b1[4];
#pragma unroll
  for (int g = 0; g < 4; ++g) {
    b0[g] = dbias[g * 256 + col];
    b1[g] = dbias[1024 + g * 256 + col];
  }
  float c0 = cfb[(bg * 16 + brow) * 256 + col];
  float c1 = cbb[(bg * 16 + brow) * 256 + col];

  int gbrow = tid & 15, gcg = tid >> 4;
  int gldsbase = gbrow * 512 + gcg * 32;
  int gswz = (gbrow & 7) << 4;
  {
    const float* sA = h0b + 32768 + (bg * 16 + gbrow) * 256 + gcg * 16;
    const float* sB = h1b + 32768 + (bg * 16 + gbrow) * 256 + gcg * 16;
    u32 wa[8], wb[8];
#pragma unroll
    for (int i = 0; i < 8; ++i) {
      wa[i] = packf16(sA[2 * i], sA[2 * i + 1]);
      wb[i] = packf16(sB[2 * i], sB[2 * i + 1]);
    }
    *(u32x4*)(hA + (gldsbase ^ gswz))        = (u32x4){wa[0], wa[1], wa[2], wa[3]};
    *(u32x4*)(hA + ((gldsbase + 16) ^ gswz)) = (u32x4){wa[4], wa[5], wa[6], wa[7]};
    *(u32x4*)(hB + (gldsbase ^ gswz))        = (u32x4){wb[0], wb[1], wb[2], wb[3]};
    *(u32x4*)(hB + ((gldsbase + 16) ^ gswz)) = (u32x4){wb[4], wb[5], wb[6], wb[7]};
  }
  __syncthreads();

  u64* g0 = (u64*)r0;
  u64* g1 = (u64*)r1;
  long ring = (long)bg * 4096;

  for (int t = 0; t < 64; ++t) {
    f32x4 a0 = {}, a1 = {};
    if (t > 0) {
#pragma unroll
      for (int ks = 0; ks < 8; ++ks) {
        f16x8 hf = *(const f16x8*)(hB + ((brow * 512 + ks * 64 + lq * 16) ^ hswz));
        if (ks & 1) a1 = __builtin_amdgcn_mfma_f32_16x16x32_f16(w0[ks], hf, a1, 0, 0, 0);
        else        a0 = __builtin_amdgcn_mfma_f32_16x16x32_f16(w0[ks], hf, a0, 0, 0, 0);
      }
    }
#pragma unroll
    for (int ks = 0; ks < 8; ++ks) {
      f16x8 hf = *(const f16x8*)(hA + ((brow * 512 + ks * 64 + lq * 16) ^ hswz));
      if (ks & 1) a1 = __builtin_amdgcn_mfma_f32_16x16x32_f16(w0[8 + ks], hf, a1, 0, 0, 0);
      else        a0 = __builtin_amdgcn_mfma_f32_16x16x32_f16(w0[8 + ks], hf, a0, 0, 0, 0);
    }
    {
      float iv = 1.f / (1.f + expf(-(a0[0] + a1[0] + b0[0])));
      float fv = 1.f / (1.f + expf(-(a0[1] + a1[1] + b0[1])));
      float gg = tanhf(a0[2] + a1[2] + b0[2]);
      float ov = 1.f / (1.f + expf(-(a0[3] + a1[3] + b0[3])));
      c0 = fv * c0 + iv * gg;
      float h0v = ov * tanhf(c0);
      hstage[brow][w * 4 + lq] = f2h(h0v);
    }
    __syncthreads();
    if (tid < 64)
      ast64(g0 + ring + (long)((t + 2) & 3) * 1024 + cg * 64 + tid, SENT);
    asm volatile("s_waitcnt vmcnt(0)" ::: "memory");
    if (tid < 64) {
      u64 v = *(const u64*)&hstage[tid >> 2][(tid & 3) * 4];
      ast64(g0 + ring + (long)(t & 3) * 1024 + cg * 64 + tid, v);
    }
    {
      const long gb = ring + (long)(t & 3) * 1024 + 4 * tid;
      u64 v0 = SENT, v1 = SENT, v2 = SENT, v3 = SENT;
      for (;;) {
        bool ok = true;
        if (v0 == SENT) { v0 = ald64(g0 + gb + 0); ok &= (v0 != SENT); }
        if (v1 == SENT) { v1 = ald64(g0 + gb + 1); ok &= (v1 != SENT); }
        if (v2 == SENT) { v2 = ald64(g0 + gb + 2); ok &= (v2 != SENT); }
        if (v3 == SENT) { v3 = ald64(g0 + gb + 3); ok &= (v3 != SENT); }
        if (ok) break;
      }
      *(u32x4*)(hA + (gldsbase ^ gswz)) =
          (u32x4){ (u32)v0, (u32)(v0 >> 32), (u32)v1, (u32)(v1 >> 32) };
      *(u32x4*)(hA + ((gldsbase + 16) ^ gswz)) =
          (u32x4){ (u32)v2, (u32)(v2 >> 32), (u32)v3, (u32)(v3 >> 32) };
    }
    __syncthreads();

    a0 = (f32x4){}; a1 = (f32x4){};
#pragma unroll
    for (int ks = 0; ks < 8; ++ks) {
      f16x8 hf = *(const f16x8*)(hA + ((brow * 512 + ks * 64 + lq * 16) ^ hswz));
      if (ks & 1) a1 = __builtin_amdgcn_mfma_f32_16x16x32_f16(w1[ks], hf, a1, 0, 0, 0);
      else        a0 = __builtin_amdgcn_mfma_f32_16x16x32_f16(w1[ks], hf, a0, 0, 0, 0);
    }
#pragma unroll
    for (int ks = 0; ks < 8; ++ks) {
      f16x8 hf = *(const f16x8*)(hB + ((brow * 512 + ks * 64 + lq * 16) ^ hswz));
      if (ks & 1) a1 = __builtin_amdgcn_mfma_f32_16x16x32_f16(w1[8 + ks], hf, a1, 0, 0, 0);
      else        a0 = __builtin_amdgcn_mfma_f32_16x16x32_f16(w1[8 + ks], hf, a0, 0, 0, 0);
    }
    {
      float iv = 1.f / (1.f + expf(-(a0[0] + a1[0] + b1[0])));
      float fv = 1.f / (1.f + expf(-(a0[1] + a1[1] + b1[1])));
      float gg = tanhf(a0[2] + a1[2] + b1[2]);
      float ov = 1.f / (1.f + expf(-(a0[3] + a1[3] + b1[3])));
      c1 = fv * c1 + iv * gg;
      float h1v = ov * tanhf(c1);
      hstage[brow][w * 4 + lq] = f2h(h1v);
    }
    __syncthreads();
    if (tid < 64) {
      u64 v = *(const u64*)&hstage[tid >> 2][(tid & 3) * 4];
      float4 hv4 = { h2f((u16)v), h2f((u16)(v >> 16)),
                     h2f((u16)(v >> 32)), h2f((u16)(v >> 48)) };
      *(float4*)&hist[((long)t * 128 + bg * 16 + (tid >> 2)) * 256 + cg * 16 + (tid & 3) * 4] = hv4;
    }
    if (t < 63) {
      if (tid < 64)
        ast64(g1 + ring + (long)((t + 2) & 3) * 1024 + cg * 64 + tid, SENT);
      asm volatile("s_waitcnt vmcnt(0)" ::: "memory");
      if (tid < 64) {
        u64 v = *(const u64*)&hstage[tid >> 2][(tid & 3) * 4];
        ast64(g1 + ring + (long)(t & 3) * 1024 + cg * 64 + tid, v);
      }
      const long gb = ring + (long)(t & 3) * 1024 + 4 * tid;
      u64 v0 = SENT, v1 = SENT, v2 = SENT, v3 = SENT;
      for (;;) {
        bool ok = true;
        if (v0 == SENT) { v0 = ald64(g1 + gb + 0); ok &= (v0 != SENT); }
        if (v1 == SENT) { v1 = ald64(g1 + gb + 1); ok &= (v1 != SENT); }
        if (v2 == SENT) { v2 = ald64(g1 + gb + 2); ok &= (v2 != SENT); }
        if (v3 == SENT) { v3 = ald64(g1 + gb + 3); ok &= (v3 != SENT); }
        if (ok) break;
      }
      *(u32x4*)(hB + (gldsbase ^ gswz)) =
          (u32x4){ (u32)v0, (u32)(v0 >> 32), (u32)v1, (u32)(v1 >> 32) };
      *(u32x4*)(hB + ((gldsbase + 16) ^ gswz)) =
          (u32x4){ (u32)v2, (u32)(v2 >> 32), (u32)v3, (u32)(v3 >> 32) };
    }
    __syncthreads();
  }
}

// ---------------------------------------------------------------------------
__global__ __launch_bounds__(256) void logits_k(
    const float* __restrict__ hist, const float* __restrict__ lw,
    const float* __restrict__ lb, float* __restrict__ out) {
  int widx = threadIdx.x >> 6, lane = threadIdx.x & 63;
  int row = blockIdx.x * 4 + widx;
  const float* h = hist + (long)row * 256;
  float4 hv = *(const float4*)&h[lane * 4];
  float s[3];
#pragma unroll
  for (int v = 0; v < 3; ++v) {
    float4 wv = *(const float4*)&lw[v * 256 + lane * 4];
    float p = hv.x * wv.x + hv.y * wv.y + hv.z * wv.z + hv.w * wv.w;
#pragma unroll
    for (int o = 32; o > 0; o >>= 1) p += __shfl_xor(p, o, 64);
    s[v] = p;
  }
  if (lane == 0) {
    out[row * 3 + 0] = s[0] + lb[0];
    out[row * 3 + 1] = s[1] + lb[1];
    out[row * 3 + 2] = s[2] + lb[2];
  }
}

// ---------------------------------------------------------------------------
extern "C" void kernel_launch(void* const* d_in, const int* in_sizes, int n_in,
                              void* d_out, int out_size, void* d_ws, size_t ws_size,
                              hipStream_t stream) {
  const float* x     = (const float*)d_in[0];
  const float* ewihf = (const float*)d_in[1];
  const float* ewhhf = (const float*)d_in[2];
  const float* ebihf = (const float*)d_in[3];
  const float* ebhhf = (const float*)d_in[4];
  const float* ewihb = (const float*)d_in[5];
  const float* ewhhb = (const float*)d_in[6];
  const float* ebihb = (const float*)d_in[7];
  const float* ebhhb = (const float*)d_in[8];
  const float* dwih0 = (const float*)d_in[9];
  const float* dwhh0 = (const float*)d_in[10];
  const float* dbih0 = (const float*)d_in[11];
  const float* dbhh0 = (const float*)d_in[12];
  const float* dwih1 = (const float*)d_in[13];
  const float* dwhh1 = (const float*)d_in[14];
  const float* dbih1 = (const float*)d_in[15];
  const float* dbhh1 = (const float*)d_in[16];
  const float* lw    = (const float*)d_in[17];
  const float* lb    = (const float*)d_in[18];
  float* out = (float*)d_out;
  (void)in_sizes; (void)n_in; (void)out_size; (void)ws_size;

  char* wsb = (char*)d_ws;
  size_t off = 0;
  auto take = [&](size_t bytes) -> char* {
    char* p = wsb + off;
    off = (off + bytes + 255) & ~(size_t)255;
    return p;
  };
  u16*   xh    = (u16*)take(67108864ull * 2);    // x f16
  u16*   whx   = (u16*)take(2097152ull * 2);     // ew_ih f,b f16
  float* xp    = (float*)take(134217728ull * 4); // Xproj [2][512][128][1024] fp32
  u16*   wenc4 = (u16*)take(524288ull * 2);      // enc W_hh fan-2 frags
  u16*   wdec  = (u16*)take(1048576ull * 2);     // dec both-layer frags
  float* bias2 = (float*)take(2048 * 4);
  float* dbias = (float*)take(2048 * 4);
  u32*   hglob = (u32*)take(131072ull * 4);      // enc rings [32][4 slot][512 u64]
  u32*   r0    = (u32*)take(65536ull * 4);       // dec h0 ring
  u32*   r1    = (u32*)take(65536ull * 4);       // dec h1 ring
  float* h0b   = (float*)take(65536 * 4);
  float* h1b   = (float*)take(65536 * 4);
  float* cfb   = (float*)take(32768 * 4);
  float* cbb   = (float*)take(32768 * 4);
  float* hist  = (float*)take(2097152 * 4);      // h1 history [64][128][256] f32

  init_k<<<1024, 256, 0, stream>>>(hglob, r0, r1);
  convert_k<<<2048, 256, 0, stream>>>(x, ewihf, ewihb, ebihf, ebhhf, ebihb, ebhhb,
                                      dbih0, dbhh0, dbih1, dbhh1, xh, whx, bias2, dbias);
  convert_we4_k<<<2048, 256, 0, stream>>>(ewhhf, ewhhb, wenc4);
  convert_wdec_k<<<4096, 256, 0, stream>>>(dwih0, dwhh0, dwih1, dwhh1, wdec);
  xproj_gemm<<<8192, 256, 0, stream>>>(xh, whx, bias2, xp);
  encoder_k<<<32, 512, 0, stream>>>(wenc4, xp, hglob, h0b, h1b, cfb, cbb);
  decoder_k<<<128, 256, 0, stream>>>(wdec, dbias, h0b, h1b, cfb, cbb, r0, r1, hist);
  logits_k<<<2048, 256, 0, stream>>>(hist, lw, lb, out);
}

// Round 16
// 1956.042 us; speedup vs baseline: 2.2217x; 2.2217x over previous
//
#include <hip/hip_runtime.h>
#include <hip/hip_bf16.h>
#include <math.h>

// ---------------------------------------------------------------------------
// Bi-LSTM encoder (final states only) -> 2-layer AR decoder (64 steps) -> vocab-3.
//   init_k         : sentinel encoder h-ring + decoder rings r0/r1
//   convert_k      : x, ew_ih_{f,b} -> f16; bias sums
//   convert_we3_k  : enc W_hh -> gate-interleaved MFMA A-fragments (f16)
//   convert_wdec_k : dec [W_ih|W_hh] both layers -> gate-interleaved A-frags (f16)
//   xproj_gemm     : v2 — global_load_lds staging (m97 recipe): linear [128][32]
//                    LDS, pre-swizzled global source, XOR'd fragment reads
//   encoder_k      : v9b (R12-proven, byte-identical) — depth-4 sentinel ring
//   decoder_k      : v3b (R12-proven) — dual-layer blocks, two sentinel rings
//   logits_k       : h1 history @ lw^T + lb
// ---------------------------------------------------------------------------

typedef unsigned short u16;
typedef unsigned int u32;
typedef unsigned long long u64;
typedef _Float16 f16;
typedef f16 f16x8 __attribute__((ext_vector_type(8)));
typedef u16 u16x8 __attribute__((ext_vector_type(8)));
typedef u32 u32x4 __attribute__((ext_vector_type(4)));
typedef float f32x4 __attribute__((ext_vector_type(4)));

__device__ __forceinline__ u16 f2h(float f) {
  return __builtin_bit_cast(unsigned short, (f16)f);
}
__device__ __forceinline__ float h2f(u16 h) {
  return (float)__builtin_bit_cast(f16, h);
}
__device__ __forceinline__ u32 packf16(float a, float b) {
  return (u32)f2h(a) | ((u32)f2h(b) << 16);
}
__device__ __forceinline__ u64 ald64(const u64* p) {
  return __hip_atomic_load(p, __ATOMIC_RELAXED, __HIP_MEMORY_SCOPE_AGENT);
}
__device__ __forceinline__ void ast64(u64* p, u64 v) {
  __hip_atomic_store(p, v, __ATOMIC_RELAXED, __HIP_MEMORY_SCOPE_AGENT);
}
__device__ __forceinline__ void gload16(const void* g, void* l) {
  __builtin_amdgcn_global_load_lds(
      (const __attribute__((address_space(1))) void*)g,
      (__attribute__((address_space(3))) void*)l, 16, 0, 0);
}

#define SENT 0xFFFFFFFFFFFFFFFFull   // f16 NaN quad: unreachable for h in (-1,1)

// ---------------------------------------------------------------------------
__global__ __launch_bounds__(256) void init_k(u32* hglob, u32* r0, u32* r1) {
  int gid = blockIdx.x * 256 + threadIdx.x;   // grid 1024*256 = 262144
  if (gid < 131072)       hglob[gid] = 0xFFFFFFFFu;
  else if (gid < 196608)  r0[gid - 131072] = 0xFFFFFFFFu;
  else                    r1[gid - 196608] = 0xFFFFFFFFu;
}

// ---------------------------------------------------------------------------
__global__ __launch_bounds__(256) void convert_k(
    const float* __restrict__ x,
    const float* __restrict__ wfm, const float* __restrict__ wbm,
    const float* __restrict__ bif, const float* __restrict__ bhf,
    const float* __restrict__ bib, const float* __restrict__ bhb,
    const float* __restrict__ dbi0, const float* __restrict__ dbh0,
    const float* __restrict__ dbi1, const float* __restrict__ dbh1,
    u16* __restrict__ xh, u16* __restrict__ wh,
    float* __restrict__ bias2, float* __restrict__ dbias) {
  const long NX = 67108864L, NW = 1048576L;
  long gid = (long)blockIdx.x * 256 + threadIdx.x;
  if (gid < 1024) {
    bias2[gid]        = bif[gid] + bhf[gid];
    bias2[1024 + gid] = bib[gid] + bhb[gid];
    dbias[gid]        = dbi0[gid] + dbh0[gid];
    dbias[1024 + gid] = dbi1[gid] + dbh1[gid];
  }
  long total4 = (NX + 2 * NW) >> 2;
  long stride = (long)gridDim.x * 256;
  for (long q = gid; q < total4; q += stride) {
    long i = q << 2;
    const float* src; u16* dst; long o;
    if (i < NX)            { src = x;   dst = xh;      o = i; }
    else if (i < NX + NW)  { src = wfm; dst = wh;      o = i - NX; }
    else                   { src = wbm; dst = wh + NW; o = i - NX - NW; }
    float4 v = *(const float4*)&src[o];
    dst[o + 0] = f2h(v.x); dst[o + 1] = f2h(v.y);
    dst[o + 2] = f2h(v.z); dst[o + 3] = f2h(v.w);
  }
}

// ---------------------------------------------------------------------------
// enc W_hh -> gate-interleaved A-fragments:
//   wenc3[d][cg][w][ks][lane][j] = W_hh_d[gcol][ks*32 + (lane>>4)*8 + j]
//   with ri = lane&15, gcol = (ri&3)*256 + cg*16 + w*4 + (ri>>2).
__global__ __launch_bounds__(256) void convert_we3_k(
    const float* __restrict__ whf, const float* __restrict__ whb,
    u16* __restrict__ wenc3) {
  int o = blockIdx.x * 256 + threadIdx.x;     // grid 2048*256 = 524288
  int j = o & 7, lane = (o >> 3) & 63, ks = (o >> 9) & 7;
  int w = (o >> 12) & 3, cg = (o >> 14) & 15, d = o >> 18;
  int ri = lane & 15;
  int gcol = (ri & 3) * 256 + cg * 16 + w * 4 + (ri >> 2);
  int k = ks * 32 + (lane >> 4) * 8 + j;
  const float* wsrc = d ? whb : whf;
  wenc3[o] = f2h(wsrc[gcol * 256 + k]);
}

// ---------------------------------------------------------------------------
// dec [W_ih|W_hh] (K=512) both layers -> gate-interleaved A-fragments.
__global__ __launch_bounds__(256) void convert_wdec_k(
    const float* __restrict__ wi0, const float* __restrict__ wh0,
    const float* __restrict__ wi1, const float* __restrict__ wh1,
    u16* __restrict__ wdec) {
  int o = blockIdx.x * 256 + threadIdx.x;     // grid 4096*256 = 1048576
  int j = o & 7, lane = (o >> 3) & 63, ks = (o >> 9) & 15;
  int w = (o >> 13) & 3, cg = (o >> 15) & 15, L = o >> 19;
  int ri = lane & 15;
  int row = (ri & 3) * 256 + cg * 16 + w * 4 + (ri >> 2);
  int k = ks * 32 + (lane >> 4) * 8 + j;
  const float* wi = L ? wi1 : wi0;
  const float* wh = L ? wh1 : wh0;
  float v = (k < 256) ? wi[row * 256 + k] : wh[row * 256 + k - 256];
  wdec[o] = f2h(v);
}

// ---------------------------------------------------------------------------
// Xproj GEMM v2 (m97 recipe): C = X @ W^T + bias, 128x128 tiles, BK=32.
// Staging: per wave 2xA + 2xB width-16 global_load_lds (1KB each) into LINEAR
// [128][32] f16 LDS. Swizzle is rule-21-compliant: LDS dest linear; the GLOBAL
// source col-chunk is permuted (chunk ^= row&3) and the fragment read applies
// the same XOR — read conflicts drop to <=4-way, coalescing per 64B row kept.
__global__ __launch_bounds__(256) void xproj_gemm(
    const u16* __restrict__ xh, const u16* __restrict__ wh,
    const float* __restrict__ bias2, float* __restrict__ xp) {
  __shared__ __align__(16) u16 Als[128 * 32];
  __shared__ __align__(16) u16 Bls[128 * 32];
  int bid = blockIdx.x;
  int dir = bid >> 12, rem = bid & 4095, tb = rem >> 3, nb = rem & 7;
  int tsrc = dir ? (511 - tb) : tb;
  const u16* A  = xh + (long)tsrc * (128 * 1024);
  const u16* Bw = wh + (long)dir * (1024 * 1024) + (long)nb * (128 * 1024);
  float* C = xp + ((long)(dir * 512 + tb) * 128) * 1024 + nb * 128;
  const float* bias = bias2 + dir * 1024 + nb * 128;

  int tid = threadIdx.x, lane = tid & 63, wid = tid >> 6;
  int wr = wid >> 1, wc = wid & 1;
  int fr = lane & 15, ko = lane >> 4;

  // staging decode: instr i of wave wid covers rows wid*32 + i*16 .. +15;
  // lane l -> row += l>>2, physical chunk p = l&3 holds global chunk p^(row&3)
  int srow0 = wid * 32 + (lane >> 2);
  int srow1 = srow0 + 16;
  int sc0 = (((lane & 3) ^ (srow0 & 3)) * 8);
  int sc1 = (((lane & 3) ^ (srow1 & 3)) * 8);
  char* lA0 = (char*)Als + (wid * 2 + 0) * 1024;   // wave-uniform LDS bases
  char* lA1 = (char*)Als + (wid * 2 + 1) * 1024;
  char* lB0 = (char*)Bls + (wid * 2 + 0) * 1024;
  char* lB1 = (char*)Bls + (wid * 2 + 1) * 1024;

  f32x4 acc[4][4] = {};
  for (int k0 = 0; k0 < 1024; k0 += 32) {
    __syncthreads();   // prior iter's fragment reads complete before overwrite
    gload16(&A [(long)srow0 * 1024 + k0 + sc0], lA0);
    gload16(&A [(long)srow1 * 1024 + k0 + sc1], lA1);
    gload16(&Bw[(long)srow0 * 1024 + k0 + sc0], lB0);
    gload16(&Bw[(long)srow1 * 1024 + k0 + sc1], lB1);
    __syncthreads();   // compiler drains vmcnt before barrier -> staging visible
    f16x8 af[4], bf[4];
#pragma unroll
    for (int i = 0; i < 4; ++i) {
      int ra = wr * 64 + i * 16 + fr;
      af[i] = *(const f16x8*)((const char*)Als + ra * 64 + ((ko ^ (ra & 3)) * 16));
    }
#pragma unroll
    for (int jf = 0; jf < 4; ++jf) {
      int rb = wc * 64 + jf * 16 + fr;
      bf[jf] = *(const f16x8*)((const char*)Bls + rb * 64 + ((ko ^ (rb & 3)) * 16));
    }
#pragma unroll
    for (int i = 0; i < 4; ++i)
#pragma unroll
      for (int jf = 0; jf < 4; ++jf)
        acc[i][jf] = __builtin_amdgcn_mfma_f32_16x16x32_f16(af[i], bf[jf], acc[i][jf], 0, 0, 0);
  }
  int fq = lane >> 4;
#pragma unroll
  for (int i = 0; i < 4; ++i)
#pragma unroll
    for (int jf = 0; jf < 4; ++jf) {
      int col = wc * 64 + jf * 16 + fr;
      float bv = bias[col];
#pragma unroll
      for (int e = 0; e < 4; ++e) {
        int row = wr * 64 + i * 16 + fq * 4 + e;
        C[(long)row * 1024 + col] = acc[i][jf][e] + bv;
      }
    }
}

// ---------------------------------------------------------------------------
// Encoder v9b (R12-proven, byte-identical).
__global__ __launch_bounds__(256, 1) void encoder_k(
    const u16* __restrict__ wenc3, const float* __restrict__ xp,
    u32* hglob,
    float* h0b, float* h1b, float* cfb, float* cbb) {
  int b = blockIdx.x;
  int g16 = ((b >> 7) << 3) | (b & 7);
  int cg = (b >> 3) & 15;
  int d = g16 >> 3, bg = g16 & 7;
  int tid = threadIdx.x, lane = tid & 63, w = tid >> 6;
  int brow = lane & 15, lq = lane >> 4;
  int hswz = (brow & 7) << 4;

  __shared__ __align__(16) char hlds[2][8192];
  __shared__ __align__(16) u16 hstage[16][16];

  f16x8 wfr[8];
  {
    const u16* wb = wenc3 + (((long)d * 16 + cg) * 4 + w) * 4096 + lane * 8;
#pragma unroll
    for (int ks = 0; ks < 8; ++ks)
      wfr[ks] = __builtin_bit_cast(f16x8, *(const u16x8*)(wb + (long)ks * 512));
  }

  float c_state = 0.f;
  long xpbase = ((long)(d * 512) * 128 + bg * 16 + brow) * 1024 + cg * 16 + w * 4 + lq;
  float xpv[4];
#pragma unroll
  for (int g = 0; g < 4; ++g) xpv[g] = xp[xpbase + g * 256];

  u64* hg = (u64*)hglob;
  long ringbase = (long)g16 * 4096;
  int gcg = tid >> 4, gbrow = tid & 15;
  int gldsbase = gbrow * 512 + gcg * 32;
  int gswz = (gbrow & 7) << 4;
  __syncthreads();

  for (int t = 0; t < 512; ++t) {
    if (t != 0) {
      const long gb = ringbase + (long)(t & 3) * 1024 + 4 * tid;
      u64 v0 = SENT, v1 = SENT, v2 = SENT, v3 = SENT;
      for (;;) {
        bool ok = true;
        if (v0 == SENT) { v0 = ald64(hg + gb + 0); ok &= (v0 != SENT); }
        if (v1 == SENT) { v1 = ald64(hg + gb + 1); ok &= (v1 != SENT); }
        if (v2 == SENT) { v2 = ald64(hg + gb + 2); ok &= (v2 != SENT); }
        if (v3 == SENT) { v3 = ald64(hg + gb + 3); ok &= (v3 != SENT); }
        if (ok) break;
      }
      if (tid < 64)
        ast64(hg + ringbase + (long)((t + 2) & 3) * 1024 + cg * 64 + tid, SENT);
      char* hwr = hlds[t & 1];
      *(u32x4*)(hwr + (gldsbase ^ gswz)) =
          (u32x4){ (u32)v0, (u32)(v0 >> 32), (u32)v1, (u32)(v1 >> 32) };
      *(u32x4*)(hwr + ((gldsbase + 16) ^ gswz)) =
          (u32x4){ (u32)v2, (u32)(v2 >> 32), (u32)v3, (u32)(v3 >> 32) };
    }
    __syncthreads();

    f32x4 acc0 = {}, acc1 = {};
    if (t != 0) {
      const char* hrd = hlds[t & 1];
#pragma unroll
      for (int ks = 0; ks < 8; ++ks) {
        f16x8 hf = *(const f16x8*)(hrd + ((brow * 512 + ks * 64 + lq * 16) ^ hswz));
        if (ks & 1) acc1 = __builtin_amdgcn_mfma_f32_16x16x32_f16(wfr[ks], hf, acc1, 0, 0, 0);
        else        acc0 = __builtin_amdgcn_mfma_f32_16x16x32_f16(wfr[ks], hf, acc0, 0, 0, 0);
      }
    }

    float iv = 1.f / (1.f + expf(-(acc0[0] + acc1[0] + xpv[0])));
    float fv = 1.f / (1.f + expf(-(acc0[1] + acc1[1] + xpv[1])));
    float gg = tanhf(acc0[2] + acc1[2] + xpv[2]);
    float ov = 1.f / (1.f + expf(-(acc0[3] + acc1[3] + xpv[3])));
    c_state = fv * c_state + iv * gg;
    float hval = ov * tanhf(c_state);

    if (t < 511) {
      hstage[brow][w * 4 + lq] = f2h(hval);
      __syncthreads();
      asm volatile("s_waitcnt vmcnt(0)" ::: "memory");
      if (tid < 64) {
        u64 v = *(const u64*)&hstage[tid >> 2][(tid & 3) * 4];
        ast64(hg + ringbase + (long)((t + 1) & 3) * 1024 + cg * 64 + tid, v);
      }
      long xb2 = xpbase + (long)(t + 1) * 131072;
#pragma unroll
      for (int g = 0; g < 4; ++g) xpv[g] = xp[xb2 + g * 256];
    } else {
      int rowg = bg * 16 + brow, colg = cg * 16 + w * 4 + lq;
      (d ? h1b : h0b)[32768 + rowg * 256 + colg] = hval;
      (d ? cbb : cfb)[rowg * 256 + colg] = c_state;
    }
  }
}

// ---------------------------------------------------------------------------
// Decoder v3b (R12-proven, unchanged).
__global__ __launch_bounds__(256, 1) void decoder_k(
    const u16* __restrict__ wdec, const float* __restrict__ dbias,
    const float* __restrict__ h0b, const float* __restrict__ h1b,
    const float* __restrict__ cfb, const float* __restrict__ cbb,
    u32* r0, u32* r1, float* __restrict__ hist) {
  int b = blockIdx.x;
  int bg = b & 7, cg = b >> 3;
  int tid = threadIdx.x, lane = tid & 63, w = tid >> 6;
  int brow = lane & 15, lq = lane >> 4;
  int hswz = (brow & 7) << 4;
  int col = cg * 16 + w * 4 + lq;

  __shared__ __align__(16) char hA[8192];
  __shared__ __align__(16) char hB[8192];
  __shared__ __align__(16) u16 hstage[16][16];

  f16x8 w0[16], w1[16];
  {
    const u16* p0 = wdec + ((long)(cg * 4 + w)) * 8192 + lane * 8;
    const u16* p1 = wdec + ((long)((16 + cg) * 4 + w)) * 8192 + lane * 8;
#pragma unroll
    for (int ks = 0; ks < 16; ++ks) {
      w0[ks] = __builtin_bit_cast(f16x8, *(const u16x8*)(p0 + (long)ks * 512));
      w1[ks] = __builtin_bit_cast(f16x8, *(const u16x8*)(p1 + (long)ks * 512));
    }
  }
  float b0[4], b1[4];
#pragma unroll
  for (int g = 0; g < 4; ++g) {
    b0[g] = dbias[g * 256 + col];
    b1[g] = dbias[1024 + g * 256 + col];
  }
  float c0 = cfb[(bg * 16 + brow) * 256 + col];
  float c1 = cbb[(bg * 16 + brow) * 256 + col];

  int gbrow = tid & 15, gcg = tid >> 4;
  int gldsbase = gbrow * 512 + gcg * 32;
  int gswz = (gbrow & 7) << 4;
  {
    const float* sA = h0b + 32768 + (bg * 16 + gbrow) * 256 + gcg * 16;
    const float* sB = h1b + 32768 + (bg * 16 + gbrow) * 256 + gcg * 16;
    u32 wa[8], wb[8];
#pragma unroll
    for (int i = 0; i < 8; ++i) {
      wa[i] = packf16(sA[2 * i], sA[2 * i + 1]);
      wb[i] = packf16(sB[2 * i], sB[2 * i + 1]);
    }
    *(u32x4*)(hA + (gldsbase ^ gswz))        = (u32x4){wa[0], wa[1], wa[2], wa[3]};
    *(u32x4*)(hA + ((gldsbase + 16) ^ gswz)) = (u32x4){wa[4], wa[5], wa[6], wa[7]};
    *(u32x4*)(hB + (gldsbase ^ gswz))        = (u32x4){wb[0], wb[1], wb[2], wb[3]};
    *(u32x4*)(hB + ((gldsbase + 16) ^ gswz)) = (u32x4){wb[4], wb[5], wb[6], wb[7]};
  }
  __syncthreads();

  u64* g0 = (u64*)r0;
  u64* g1 = (u64*)r1;
  long ring = (long)bg * 4096;

  for (int t = 0; t < 64; ++t) {
    // ===== L0: gates = [inp | h0_{t-1}] @ W0^T ; inp_0 = 0 (skip hB part) =====
    f32x4 a0 = {}, a1 = {};
    if (t > 0) {
#pragma unroll
      for (int ks = 0; ks < 8; ++ks) {
        f16x8 hf = *(const f16x8*)(hB + ((brow * 512 + ks * 64 + lq * 16) ^ hswz));
        if (ks & 1) a1 = __builtin_amdgcn_mfma_f32_16x16x32_f16(w0[ks], hf, a1, 0, 0, 0);
        else        a0 = __builtin_amdgcn_mfma_f32_16x16x32_f16(w0[ks], hf, a0, 0, 0, 0);
      }
    }
#pragma unroll
    for (int ks = 0; ks < 8; ++ks) {
      f16x8 hf = *(const f16x8*)(hA + ((brow * 512 + ks * 64 + lq * 16) ^ hswz));
      if (ks & 1) a1 = __builtin_amdgcn_mfma_f32_16x16x32_f16(w0[8 + ks], hf, a1, 0, 0, 0);
      else        a0 = __builtin_amdgcn_mfma_f32_16x16x32_f16(w0[8 + ks], hf, a0, 0, 0, 0);
    }
    {
      float iv = 1.f / (1.f + expf(-(a0[0] + a1[0] + b0[0])));
      float fv = 1.f / (1.f + expf(-(a0[1] + a1[1] + b0[1])));
      float gg = tanhf(a0[2] + a1[2] + b0[2]);
      float ov = 1.f / (1.f + expf(-(a0[3] + a1[3] + b0[3])));
      c0 = fv * c0 + iv * gg;
      float h0v = ov * tanhf(c0);
      hstage[brow][w * 4 + lq] = f2h(h0v);
    }
    __syncthreads();
    if (tid < 64)
      ast64(g0 + ring + (long)((t + 2) & 3) * 1024 + cg * 64 + tid, SENT);
    asm volatile("s_waitcnt vmcnt(0)" ::: "memory");
    if (tid < 64) {
      u64 v = *(const u64*)&hstage[tid >> 2][(tid & 3) * 4];
      ast64(g0 + ring + (long)(t & 3) * 1024 + cg * 64 + tid, v);
    }
    {
      const long gb = ring + (long)(t & 3) * 1024 + 4 * tid;
      u64 v0 = SENT, v1 = SENT, v2 = SENT, v3 = SENT;
      for (;;) {
        bool ok = true;
        if (v0 == SENT) { v0 = ald64(g0 + gb + 0); ok &= (v0 != SENT); }
        if (v1 == SENT) { v1 = ald64(g0 + gb + 1); ok &= (v1 != SENT); }
        if (v2 == SENT) { v2 = ald64(g0 + gb + 2); ok &= (v2 != SENT); }
        if (v3 == SENT) { v3 = ald64(g0 + gb + 3); ok &= (v3 != SENT); }
        if (ok) break;
      }
      *(u32x4*)(hA + (gldsbase ^ gswz)) =
          (u32x4){ (u32)v0, (u32)(v0 >> 32), (u32)v1, (u32)(v1 >> 32) };
      *(u32x4*)(hA + ((gldsbase + 16) ^ gswz)) =
          (u32x4){ (u32)v2, (u32)(v2 >> 32), (u32)v3, (u32)(v3 >> 32) };
    }
    __syncthreads();

    // ===== L1: gates = [hA(h0_t) | hB(h1_{t-1})] @ W1^T =====
    a0 = (f32x4){}; a1 = (f32x4){};
#pragma unroll
    for (int ks = 0; ks < 8; ++ks) {
      f16x8 hf = *(const f16x8*)(hA + ((brow * 512 + ks * 64 + lq * 16) ^ hswz));
      if (ks & 1) a1 = __builtin_amdgcn_mfma_f32_16x16x32_f16(w1[ks], hf, a1, 0, 0, 0);
      else        a0 = __builtin_amdgcn_mfma_f32_16x16x32_f16(w1[ks], hf, a0, 0, 0, 0);
    }
#pragma unroll
    for (int ks = 0; ks < 8; ++ks) {
      f16x8 hf = *(const f16x8*)(hB + ((brow * 512 + ks * 64 + lq * 16) ^ hswz));
      if (ks & 1) a1 = __builtin_amdgcn_mfma_f32_16x16x32_f16(w1[8 + ks], hf, a1, 0, 0, 0);
      else        a0 = __builtin_amdgcn_mfma_f32_16x16x32_f16(w1[8 + ks], hf, a0, 0, 0, 0);
    }
    {
      float iv = 1.f / (1.f + expf(-(a0[0] + a1[0] + b1[0])));
      float fv = 1.f / (1.f + expf(-(a0[1] + a1[1] + b1[1])));
      float gg = tanhf(a0[2] + a1[2] + b1[2]);
      float ov = 1.f / (1.f + expf(-(a0[3] + a1[3] + b1[3])));
      c1 = fv * c1 + iv * gg;
      float h1v = ov * tanhf(c1);
      hstage[brow][w * 4 + lq] = f2h(h1v);
    }
    __syncthreads();
    if (tid < 64) {
      u64 v = *(const u64*)&hstage[tid >> 2][(tid & 3) * 4];
      float4 hv4 = { h2f((u16)v), h2f((u16)(v >> 16)),
                     h2f((u16)(v >> 32)), h2f((u16)(v >> 48)) };
      *(float4*)&hist[((long)t * 128 + bg * 16 + (tid >> 2)) * 256 + cg * 16 + (tid & 3) * 4] = hv4;
    }
    if (t < 63) {
      if (tid < 64)
        ast64(g1 + ring + (long)((t + 2) & 3) * 1024 + cg * 64 + tid, SENT);
      asm volatile("s_waitcnt vmcnt(0)" ::: "memory");
      if (tid < 64) {
        u64 v = *(const u64*)&hstage[tid >> 2][(tid & 3) * 4];
        ast64(g1 + ring + (long)(t & 3) * 1024 + cg * 64 + tid, v);
      }
      const long gb = ring + (long)(t & 3) * 1024 + 4 * tid;
      u64 v0 = SENT, v1 = SENT, v2 = SENT, v3 = SENT;
      for (;;) {
        bool ok = true;
        if (v0 == SENT) { v0 = ald64(g1 + gb + 0); ok &= (v0 != SENT); }
        if (v1 == SENT) { v1 = ald64(g1 + gb + 1); ok &= (v1 != SENT); }
        if (v2 == SENT) { v2 = ald64(g1 + gb + 2); ok &= (v2 != SENT); }
        if (v3 == SENT) { v3 = ald64(g1 + gb + 3); ok &= (v3 != SENT); }
        if (ok) break;
      }
      *(u32x4*)(hB + (gldsbase ^ gswz)) =
          (u32x4){ (u32)v0, (u32)(v0 >> 32), (u32)v1, (u32)(v1 >> 32) };
      *(u32x4*)(hB + ((gldsbase + 16) ^ gswz)) =
          (u32x4){ (u32)v2, (u32)(v2 >> 32), (u32)v3, (u32)(v3 >> 32) };
    }
    __syncthreads();
  }
}

// ---------------------------------------------------------------------------
__global__ __launch_bounds__(256) void logits_k(
    const float* __restrict__ hist, const float* __restrict__ lw,
    const float* __restrict__ lb, float* __restrict__ out) {
  int widx = threadIdx.x >> 6, lane = threadIdx.x & 63;
  int row = blockIdx.x * 4 + widx;
  const float* h = hist + (long)row * 256;
  float4 hv = *(const float4*)&h[lane * 4];
  float s[3];
#pragma unroll
  for (int v = 0; v < 3; ++v) {
    float4 wv = *(const float4*)&lw[v * 256 + lane * 4];
    float p = hv.x * wv.x + hv.y * wv.y + hv.z * wv.z + hv.w * wv.w;
#pragma unroll
    for (int o = 32; o > 0; o >>= 1) p += __shfl_xor(p, o, 64);
    s[v] = p;
  }
  if (lane == 0) {
    out[row * 3 + 0] = s[0] + lb[0];
    out[row * 3 + 1] = s[1] + lb[1];
    out[row * 3 + 2] = s[2] + lb[2];
  }
}

// ---------------------------------------------------------------------------
extern "C" void kernel_launch(void* const* d_in, const int* in_sizes, int n_in,
                              void* d_out, int out_size, void* d_ws, size_t ws_size,
                              hipStream_t stream) {
  const float* x     = (const float*)d_in[0];
  const float* ewihf = (const float*)d_in[1];
  const float* ewhhf = (const float*)d_in[2];
  const float* ebihf = (const float*)d_in[3];
  const float* ebhhf = (const float*)d_in[4];
  const float* ewihb = (const float*)d_in[5];
  const float* ewhhb = (const float*)d_in[6];
  const float* ebihb = (const float*)d_in[7];
  const float* ebhhb = (const float*)d_in[8];
  const float* dwih0 = (const float*)d_in[9];
  const float* dwhh0 = (const float*)d_in[10];
  const float* dbih0 = (const float*)d_in[11];
  const float* dbhh0 = (const float*)d_in[12];
  const float* dwih1 = (const float*)d_in[13];
  const float* dwhh1 = (const float*)d_in[14];
  const float* dbih1 = (const float*)d_in[15];
  const float* dbhh1 = (const float*)d_in[16];
  const float* lw    = (const float*)d_in[17];
  const float* lb    = (const float*)d_in[18];
  float* out = (float*)d_out;
  (void)in_sizes; (void)n_in; (void)out_size; (void)ws_size;

  char* wsb = (char*)d_ws;
  size_t off = 0;
  auto take = [&](size_t bytes) -> char* {
    char* p = wsb + off;
    off = (off + bytes + 255) & ~(size_t)255;
    return p;
  };
  u16*   xh    = (u16*)take(67108864ull * 2);    // x f16
  u16*   whx   = (u16*)take(2097152ull * 2);     // ew_ih f,b f16
  float* xp    = (float*)take(134217728ull * 4); // Xproj [2][512][128][1024] fp32
  u16*   wenc3 = (u16*)take(524288ull * 2);      // enc W_hh gate-interleaved frags
  u16*   wdec  = (u16*)take(1048576ull * 2);     // dec both-layer frags
  float* bias2 = (float*)take(2048 * 4);
  float* dbias = (float*)take(2048 * 4);
  u32*   hglob = (u32*)take(131072ull * 4);      // enc h ring [16g][4 slot][1024 u64]
  u32*   r0    = (u32*)take(65536ull * 4);       // dec h0 ring
  u32*   r1    = (u32*)take(65536ull * 4);       // dec h1 ring
  float* h0b   = (float*)take(65536 * 4);
  float* h1b   = (float*)take(65536 * 4);
  float* cfb   = (float*)take(32768 * 4);
  float* cbb   = (float*)take(32768 * 4);
  float* hist  = (float*)take(2097152 * 4);      // h1 history [64][128][256] f32

  init_k<<<1024, 256, 0, stream>>>(hglob, r0, r1);
  convert_k<<<2048, 256, 0, stream>>>(x, ewihf, ewihb, ebihf, ebhhf, ebihb, ebhhb,
                                      dbih0, dbhh0, dbih1, dbhh1, xh, whx, bias2, dbias);
  convert_we3_k<<<2048, 256, 0, stream>>>(ewhhf, ewhhb, wenc3);
  convert_wdec_k<<<4096, 256, 0, stream>>>(dwih0, dwhh0, dwih1, dwhh1, wdec);
  xproj_gemm<<<8192, 256, 0, stream>>>(xh, whx, bias2, xp);
  encoder_k<<<256, 256, 0, stream>>>(wenc3, xp, hglob, h0b, h1b, cfb, cbb);
  decoder_k<<<128, 256, 0, stream>>>(wdec, dbias, h0b, h1b, cfb, cbb, r0, r1, hist);
  logits_k<<<2048, 256, 0, stream>>>(hist, lw, lb, out);
}